// Round 6
// baseline (273.753 us; speedup 1.0000x reference)
//
#include <hip/hip_runtime.h>
#include <hip/hip_bf16.h>
#include <math.h>

#define BB 2
#define SS 2048
#define DD 1024
#define HH 16
#define DKK 64
#define NT (BB * SS)      // 4096 tokens

typedef __attribute__((ext_vector_type(8))) short short8;    // 8 bf16 = 4 VGPRs
typedef __attribute__((ext_vector_type(4))) float f32x4;
typedef __attribute__((ext_vector_type(16))) float f32x16;   // 32x32 MFMA acc

__device__ __forceinline__ unsigned short f2b(float x) {
    __hip_bfloat16 h = __float2bfloat16(x);   // RNE
    unsigned short u; __builtin_memcpy(&u, &h, 2); return u;
}
__device__ __forceinline__ unsigned pack2(float a, float b) {
    return (unsigned)f2b(a) | ((unsigned)f2b(b) << 16);
}

// ---------------------------------------------------------------------------
// Batched fp32 -> bf16 cast: 3 inputs + 4 weights.
// ---------------------------------------------------------------------------
struct CastAll {
    const float* src[7];
    unsigned short* dst[7];
};

__global__ __launch_bounds__(256)
void cast_all(CastAll a) {
    const int tid0 = blockIdx.x * 256 + threadIdx.x;
    const int stride = gridDim.x * 256;
    #pragma unroll
    for (int s = 0; s < 7; ++s) {
        const int n4 = (s < 3) ? (NT * DD / 4) : (DD * DD / 4);
        const float* __restrict__ src = a.src[s];
        unsigned short* __restrict__ dst = a.dst[s];
        for (int i = tid0; i < n4; i += stride) {
            const float4 v = reinterpret_cast<const float4*>(src)[i];
            ushort4 o;
            o.x = f2b(v.x); o.y = f2b(v.y); o.z = f2b(v.z); o.w = f2b(v.w);
            reinterpret_cast<ushort4*>(dst)[i] = o;
        }
    }
}

// ---------------------------------------------------------------------------
// m97-structure bf16 MFMA GEMM: C = A @ W^T + bias. 128x128 tile, BK=64,
// 4 waves, global_load_lds width-16 staging, ds_read_b128 fragments.
// MODE 0: bf16 row-major out; MODE 1: f32 row-major out;
// MODE 2: bf16 out written TRANSPOSED per head -> Vt[b][h][d][s].
// ---------------------------------------------------------------------------
template <int MODE>
__device__ __forceinline__ void gemm_body(const unsigned short* __restrict__ A,
                                          const unsigned short* __restrict__ W,
                                          const float* __restrict__ bias,
                                          void* __restrict__ Cv,
                                          int bm, int bn, int N, int K) {
    __shared__ __align__(16) unsigned char sA[128 * 128];
    __shared__ __align__(16) unsigned char sB[128 * 128];

    const int tid = threadIdx.x;
    const int l = tid & 63;
    const int w = tid >> 6;
    const int wr = w >> 1, wc = w & 1;
    const int g = l >> 4, li = l & 15;
    const int lrow = l >> 3;
    const int lcol = (l & 7) * 8;

    f32x4 acc[4][4];
    #pragma unroll
    for (int i = 0; i < 4; ++i)
        #pragma unroll
        for (int jj = 0; jj < 4; ++jj) {
            acc[i][jj][0] = 0.f; acc[i][jj][1] = 0.f;
            acc[i][jj][2] = 0.f; acc[i][jj][3] = 0.f;
        }

    for (int kt = 0; kt < K; kt += 64) {
        #pragma unroll
        for (int c = 0; c < 4; ++c) {
            const int row0 = w * 32 + c * 8;
            const unsigned short* gA = A + (size_t)(bm + row0 + lrow) * K + kt + lcol;
            __builtin_amdgcn_global_load_lds(
                (const __attribute__((address_space(1))) unsigned int*)gA,
                (__attribute__((address_space(3))) unsigned int*)&sA[row0 * 128],
                16, 0, 0);
            const unsigned short* gB = W + (size_t)(bn + row0 + lrow) * K + kt + lcol;
            __builtin_amdgcn_global_load_lds(
                (const __attribute__((address_space(1))) unsigned int*)gB,
                (__attribute__((address_space(3))) unsigned int*)&sB[row0 * 128],
                16, 0, 0);
        }
        __syncthreads();

        #pragma unroll
        for (int kb = 0; kb < 2; ++kb) {
            const int chb = (g + kb * 4) * 16;
            short8 af[4], bfr[4];
            #pragma unroll
            for (int mi = 0; mi < 4; ++mi)
                af[mi] = *reinterpret_cast<const short8*>(
                    &sA[(wr * 64 + mi * 16 + li) * 128 + chb]);
            #pragma unroll
            for (int ni = 0; ni < 4; ++ni)
                bfr[ni] = *reinterpret_cast<const short8*>(
                    &sB[(wc * 64 + ni * 16 + li) * 128 + chb]);
            #pragma unroll
            for (int mi = 0; mi < 4; ++mi)
                #pragma unroll
                for (int ni = 0; ni < 4; ++ni)
                    acc[mi][ni] = __builtin_amdgcn_mfma_f32_16x16x32_bf16(af[mi], bfr[ni], acc[mi][ni], 0, 0, 0);
        }
        __syncthreads();
    }

    // epilogue (C/D layout: col=l&15, row=(l>>4)*4+reg)
    #pragma unroll
    for (int ni = 0; ni < 4; ++ni) {
        const int col = bn + wc * 64 + ni * 16 + li;
        const float bv = bias[col];
        if constexpr (MODE == 2) {
            // transposed store: Vt[((b*16+h)*64+d) * SS + srow], 4 rows packed
            const int hh = col >> 6, d = col & 63;
            const int bb = bm >> 11;
            unsigned short* vt = (unsigned short*)Cv;
            #pragma unroll
            for (int mi = 0; mi < 4; ++mi) {
                const int srow0 = (bm & (SS - 1)) + wr * 64 + mi * 16 + g * 4;
                ushort4 pk4;
                pk4.x = f2b(acc[mi][ni][0] + bv);
                pk4.y = f2b(acc[mi][ni][1] + bv);
                pk4.z = f2b(acc[mi][ni][2] + bv);
                pk4.w = f2b(acc[mi][ni][3] + bv);
                *reinterpret_cast<ushort4*>(
                    &vt[(size_t)((bb * 16 + hh) * 64 + d) * SS + srow0]) = pk4;
            }
        } else {
            #pragma unroll
            for (int mi = 0; mi < 4; ++mi) {
                const int row0 = bm + wr * 64 + mi * 16 + g * 4;
                #pragma unroll
                for (int r = 0; r < 4; ++r) {
                    const float v = acc[mi][ni][r] + bv;
                    if constexpr (MODE == 0)
                        ((unsigned short*)Cv)[(size_t)(row0 + r) * N + col] = f2b(v);
                    else
                        ((float*)Cv)[(size_t)(row0 + r) * N + col] = v;
                }
            }
        }
    }
}

struct QKVArgs {
    const unsigned short* A[3];
    const unsigned short* W[3];
    const float* bias[3];
    unsigned short* C[2];   // q, k row-major
    unsigned short* vt;     // v transposed per head
};

__global__ __launch_bounds__(256)
void gemm_qkv(QKVArgs args) {
    const int bid = blockIdx.x;                      // 0..767
    const int i = (bid & 7) * 96 + (bid >> 3);       // bijective (768 % 8 == 0)
    const int z = i >> 8;
    const int rem = i & 255;
    const int by = rem >> 3, bx = rem & 7;
    if (z == 2)
        gemm_body<2>(args.A[2], args.W[2], args.bias[2], args.vt, by * 128, bx * 128, DD, DD);
    else
        gemm_body<0>(args.A[z], args.W[z], args.bias[z], args.C[z], by * 128, bx * 128, DD, DD);
}

__global__ __launch_bounds__(256)
void gemm_out(const unsigned short* __restrict__ A, const unsigned short* __restrict__ W,
              const float* __restrict__ bias, float* __restrict__ C) {
    const int bid = blockIdx.x;                      // 0..255
    const int i = (bid & 7) * 32 + (bid >> 3);
    const int by = i >> 3, bx = i & 7;
    gemm_body<1>(A, W, bias, C, by * 128, bx * 128, DD, DD);
}

// ---------------------------------------------------------------------------
// Causal flash attention, 32x32x16 MFMA. Block = (b, h, j): 4 waves x 32
// q-rows = 128-q block j; kv tiles 0..j of 128. K and Vt staged via
// global_load_lds (linear LDS dest, inverse-swizzled global source; read
// applies the same XOR). P stays in registers: bf16-pack + shfl_xor(32)
// half-swap re-fragments it for PV (no sP LDS). j descends with blockIdx
// so long blocks dispatch first; short ones backfill (dynamic balance).
// ---------------------------------------------------------------------------
__global__ __launch_bounds__(256)
void attn_mfma(const unsigned short* __restrict__ Q,
               const unsigned short* __restrict__ Kb,
               const unsigned short* __restrict__ Vt,
               unsigned short* __restrict__ X) {
    __shared__ __align__(16) unsigned char sK[128 * 128];   // [kv][d] chunk-swizzled
    __shared__ __align__(16) unsigned char sV[64 * 256];    // [d][kv] chunk-swizzled

    const int bid = blockIdx.x;              // 0..511
    const int xcd = bid & 7;
    const int idx = bid >> 3;                // 0..63
    const int j   = 15 - (idx >> 2);         // 15..0 (long blocks first)
    const int bh  = xcd * 4 + (idx & 3);     // (b,h) pinned 4-per-XCD
    const int b = bh >> 4, h = bh & 15;

    const int tid = threadIdx.x, l = tid & 63, w = tid >> 6;
    const int h5 = l >> 5, q5 = l & 31;
    const int col0 = h * DKK;
    const int qbase = j * 128 + w * 32;      // seq-local first q-row of wave
    const float scale = 0.125f;

    // Q fragments: B-operand, k=16s+8*h5+jj -> chunk (2s+h5)
    short8 qf[4];
    {
        const unsigned short* qp = Q + (size_t)(b * SS + qbase + q5) * DD + col0;
        #pragma unroll
        for (int s = 0; s < 4; ++s)
            qf[s] = *reinterpret_cast<const short8*>(&qp[(2 * s + h5) * 8]);
    }

    f32x16 accO[2];
    #pragma unroll
    for (int d0 = 0; d0 < 2; ++d0)
        #pragma unroll
        for (int r = 0; r < 16; ++r) accO[d0][r] = 0.f;
    float m = -INFINITY, lsum = 0.f;

    for (int kt = 0; kt <= j; ++kt) {
        // ---- stage K[128][64] and Vt[64][128] via global_load_lds ----
        {
            const unsigned short* krow = Kb + (size_t)(b * SS + kt * 128) * DD + col0;
            #pragma unroll
            for (int i = 0; i < 4; ++i) {
                const int row = w * 32 + i * 8 + (l >> 3);
                const int cj = l & 7;
                __builtin_amdgcn_global_load_lds(
                    (const __attribute__((address_space(1))) unsigned int*)
                        (krow + (size_t)row * DD + ((cj ^ (row & 7)) << 3)),
                    (__attribute__((address_space(3))) unsigned int*)&sK[w * 4096 + i * 1024],
                    16, 0, 0);
            }
            const unsigned short* vrow = Vt + (size_t)(bh * 64) * SS + kt * 128;
            #pragma unroll
            for (int i = 0; i < 4; ++i) {
                const int d = w * 16 + i * 4 + (l >> 4);
                const int cj = l & 15;
                __builtin_amdgcn_global_load_lds(
                    (const __attribute__((address_space(1))) unsigned int*)
                        (vrow + (size_t)d * SS + ((cj ^ (d & 15)) << 3)),
                    (__attribute__((address_space(3))) unsigned int*)&sV[w * 4096 + i * 1024],
                    16, 0, 0);
            }
        }
        __syncthreads();

        const bool diag = (kt == j);
        const int fact = diag ? w : 3;       // active kv fragments (wave-uniform)

        // ---- S = K . Q^T : D[kv][q], lane col q=l&31 ----
        f32x16 accS[4];
        __builtin_amdgcn_s_setprio(1);
        #pragma unroll
        for (int f = 0; f < 4; ++f) {
            if (f <= fact) {
                #pragma unroll
                for (int r = 0; r < 16; ++r) accS[f][r] = 0.f;
                #pragma unroll
                for (int s = 0; s < 4; ++s) {
                    const short8 kf = *reinterpret_cast<const short8*>(
                        &sK[(f * 32 + q5) * 128 + (((2 * s + h5) ^ (q5 & 7)) << 4)]);
                    accS[f] = __builtin_amdgcn_mfma_f32_32x32x16_bf16(kf, qf[s], accS[f], 0, 0, 0);
                }
            }
        }
        __builtin_amdgcn_s_setprio(0);

        // ---- online softmax (per-lane column q; partner lane l^32 shares q) ----
        float tmax = -INFINITY;
        #pragma unroll
        for (int f = 0; f < 4; ++f) {
            if (f <= fact) {
                #pragma unroll
                for (int r = 0; r < 16; ++r) {
                    float v = accS[f][r] * scale;
                    if (diag && f == w) {
                        const int off = (r & 3) + 8 * (r >> 2) + 4 * h5;
                        if (off > q5) v = -3e38f;
                    }
                    accS[f][r] = v;
                    tmax = fmaxf(tmax, v);
                }
            }
        }
        tmax = fmaxf(tmax, __shfl_xor(tmax, 32));

        if (!__all(tmax <= m)) {            // defer-max: skip rescale when possible
            const float mn = fmaxf(m, tmax);
            const float corr = __expf(m - mn);
            lsum *= corr;
            #pragma unroll
            for (int r = 0; r < 16; ++r) {
                const int rowloc = (r & 3) + 8 * (r >> 2) + 4 * h5;
                const float cr = __shfl(corr, rowloc | (l & 32));
                accO[0][r] *= cr;
                accO[1][r] *= cr;
            }
            m = mn;
        }

        float psum = 0.f;
        unsigned pk[32];
        #pragma unroll
        for (int f = 0; f < 4; ++f) {
            if (f <= fact) {
                #pragma unroll
                for (int i2 = 0; i2 < 8; ++i2) {
                    const float pa = __expf(accS[f][2 * i2] - m);
                    const float pb = __expf(accS[f][2 * i2 + 1] - m);
                    psum += pa + pb;
                    pk[f * 8 + i2] = pack2(pa, pb);
                }
            }
        }
        psum += __shfl_xor(psum, 32);
        lsum += psum;

        // ---- O += P . V : in-register P re-fragmentation + tr-swizzled V ----
        const int smax = diag ? (2 * w + 1) : 7;
        __builtin_amdgcn_s_setprio(1);
        #pragma unroll
        for (int s = 0; s < 8; ++s) {
            if (s <= smax) {
                const int fb = (s >> 1) * 8 + (s & 1) * 4;
                const unsigned sendA = h5 ? pk[fb + 0] : pk[fb + 2];
                const unsigned sendB = h5 ? pk[fb + 1] : pk[fb + 3];
                const unsigned rA = __shfl_xor(sendA, 32);
                const unsigned rB = __shfl_xor(sendB, 32);
                union { unsigned u[4]; short8 s8; } pf;
                pf.u[0] = h5 ? rA : pk[fb + 0];
                pf.u[1] = h5 ? rB : pk[fb + 1];
                pf.u[2] = h5 ? pk[fb + 2] : rA;
                pf.u[3] = h5 ? pk[fb + 3] : rB;
                #pragma unroll
                for (int d0 = 0; d0 < 2; ++d0) {
                    const short8 vf = *reinterpret_cast<const short8*>(
                        &sV[(d0 * 32 + q5) * 256 + (((2 * s + h5) ^ (q5 & 15)) << 4)]);
                    accO[d0] = __builtin_amdgcn_mfma_f32_32x32x16_bf16(pf.s8, vf, accO[d0], 0, 0, 0);
                }
            }
        }
        __builtin_amdgcn_s_setprio(0);
        __syncthreads();   // before next tile overwrites sK/sV
    }

    // ---- epilogue: rows q=(r&3)+8(r>>2)+4h5, col d=d0*32+q5 ----
    const float invl = 1.f / lsum;
    #pragma unroll
    for (int r = 0; r < 16; ++r) {
        const int rowloc = (r & 3) + 8 * (r >> 2) + 4 * h5;
        const float iv = __shfl(invl, rowloc | (l & 32));
        const size_t qrow = (size_t)(b * SS + qbase + rowloc) * DD + col0;
        #pragma unroll
        for (int d0 = 0; d0 < 2; ++d0)
            X[qrow + d0 * 32 + q5] = f2b(accO[d0][r] * iv);
    }
}

// ---------------------------------------------------------------------------
extern "C" void kernel_launch(void* const* d_in, const int* in_sizes, int n_in,
                              void* d_out, int out_size, void* d_ws, size_t ws_size,
                              hipStream_t stream) {
    const float* query = (const float*)d_in[0];
    const float* key   = (const float*)d_in[1];
    const float* value = (const float*)d_in[2];
    // d_in[3] = mask (guaranteed tril; causal handled structurally)
    const float* Wq = (const float*)d_in[4];
    const float* bq = (const float*)d_in[5];
    const float* Wk = (const float*)d_in[6];
    const float* bk = (const float*)d_in[7];
    const float* Wv = (const float*)d_in[8];
    const float* bv = (const float*)d_in[9];
    const float* Wo = (const float*)d_in[10];
    const float* bo = (const float*)d_in[11];
    float* out = (float*)d_out;

    unsigned short* ws16 = (unsigned short*)d_ws;
    const size_t TOK = (size_t)NT * DD;   // 4.19M elems
    const size_t WSZ = (size_t)DD * DD;   // 1.05M elems
    unsigned short* qb  = ws16;
    unsigned short* kb  = ws16 + TOK;
    unsigned short* vt  = ws16 + 2 * TOK;   // Vt[b][h][d][s]
    unsigned short* xb  = ws16 + 3 * TOK;
    unsigned short* xqb = ws16 + 4 * TOK;
    unsigned short* xkb = ws16 + 5 * TOK;
    unsigned short* xvb = ws16 + 6 * TOK;
    unsigned short* wqb = ws16 + 7 * TOK;
    unsigned short* wkb = wqb + WSZ;
    unsigned short* wvb = wkb + WSZ;
    unsigned short* wob = wvb + WSZ;

    CastAll ca;
    ca.src[0] = query; ca.dst[0] = xqb;
    ca.src[1] = key;   ca.dst[1] = xkb;
    ca.src[2] = value; ca.dst[2] = xvb;
    ca.src[3] = Wq;    ca.dst[3] = wqb;
    ca.src[4] = Wk;    ca.dst[4] = wkb;
    ca.src[5] = Wv;    ca.dst[5] = wvb;
    ca.src[6] = Wo;    ca.dst[6] = wob;
    cast_all<<<2048, 256, 0, stream>>>(ca);

    QKVArgs args;
    args.A[0] = xqb; args.A[1] = xkb; args.A[2] = xvb;
    args.W[0] = wqb; args.W[1] = wkb; args.W[2] = wvb;
    args.bias[0] = bq; args.bias[1] = bk; args.bias[2] = bv;
    args.C[0] = qb;  args.C[1] = kb;  args.vt = vt;
    gemm_qkv<<<768, 256, 0, stream>>>(args);

    attn_mfma<<<512, 256, 0, stream>>>(qb, kb, vt, xb);

    gemm_out<<<256, 256, 0, stream>>>(xb, wob, bo, out);
}